// Round 10
// baseline (282.002 us; speedup 1.0000x reference)
//
#include <hip/hip_runtime.h>
#include <hip/hip_bf16.h>

// Bahdanau attention (R10) = R6 skeleton with 4-wave blocks so 2 blocks/CU co-reside
// (cross-block overlap hides the 2-phase barrier drain - m97/m114 mechanism).
//   scores GEMM: BM=128 x BN=256 x BK=32, 256 thr / 4 waves (2Mx2N, wave 64x128,
//   acc[4][8] in AGPR ~228 unified regs/wave -> 2 waves/SIMD = 2 blocks/CU; LDS 48KB).
//   enc read once as f32 (in-reg cvt); B bf16 via global_load_lds from L2.
//   XCD swizzle: 4 sibling N-tiles of each M-strip adjacent on one XCD (enc L2 reuse).

#define NB 32
#define SS 2048
#define HD 1024
#define HE 1024
#define MM (NB * SS)   // 65536 rows
#define NT 32          // K-tiles = HE/32

typedef float f32x4 __attribute__((ext_vector_type(4)));
typedef short bf16x8 __attribute__((ext_vector_type(8)));
typedef short short4v __attribute__((ext_vector_type(4)));

static __device__ __forceinline__ short f2bf(float f) {
    union { __hip_bfloat16 h; short s; } u;
    u.h = __float2bfloat16(f);
    return u.s;
}

// async global->LDS, 16B per lane; LDS dest = wave-uniform base + lane*16.
static __device__ __forceinline__ void gload16(const void* g, const void* l) {
    __builtin_amdgcn_global_load_lds(
        (const __attribute__((address_space(1))) void*)(uintptr_t)(g),
        (__attribute__((address_space(3))) void*)(unsigned)(uintptr_t)(l),
        16, 0, 0);
}

// ---------------- f32 -> bf16 conversion (Wk only, 1M elems) ----------------
__global__ __launch_bounds__(256) void cvt_bf16_kernel(const float* __restrict__ in,
                                                       short* __restrict__ out, int n8) {
    int i = blockIdx.x * 256 + threadIdx.x;
    const int stride = gridDim.x * 256;
    for (; i < n8; i += stride) {
        const f32x4 a = *(const f32x4*)(in + (long)i * 8);
        const f32x4 b = *(const f32x4*)(in + (long)i * 8 + 4);
        bf16x8 o;
        o[0] = f2bf(a[0]); o[1] = f2bf(a[1]); o[2] = f2bf(a[2]); o[3] = f2bf(a[3]);
        o[4] = f2bf(b[0]); o[5] = f2bf(b[1]); o[6] = f2bf(b[2]); o[7] = f2bf(b[3]);
        *(bf16x8*)(out + (long)i * 8) = o;
    }
}

// ---------------- q = dh @ Wq^T : one wave per output column d ----------------
__global__ __launch_bounds__(256) void qproj_kernel(const float* __restrict__ dh,
                                                    const float* __restrict__ Wq,
                                                    float* __restrict__ q) {
    const int wid  = threadIdx.x >> 6;
    const int lane = threadIdx.x & 63;
    const int d    = blockIdx.x * 4 + wid;
    const float* wrow = Wq + (long)d * HD + lane * 16;
    f32x4 w0 = *(const f32x4*)(wrow + 0);
    f32x4 w1 = *(const f32x4*)(wrow + 4);
    f32x4 w2 = *(const f32x4*)(wrow + 8);
    f32x4 w3 = *(const f32x4*)(wrow + 12);
    for (int b = 0; b < NB; ++b) {
        const float* drow = dh + b * HD + lane * 16;
        f32x4 d0 = *(const f32x4*)(drow + 0);
        f32x4 d1 = *(const f32x4*)(drow + 4);
        f32x4 d2 = *(const f32x4*)(drow + 8);
        f32x4 d3 = *(const f32x4*)(drow + 12);
        f32x4 s4 = w0 * d0 + w1 * d1 + w2 * d2 + w3 * d3;
        float dot = s4[0] + s4[1] + s4[2] + s4[3];
        #pragma unroll
        for (int off = 32; off > 0; off >>= 1)
            dot += __shfl_xor(dot, off, 64);
        if (lane == 0) q[b * HD + d] = dot;
    }
}

// ---------------- fused score GEMM: 128 rows x 256 cols per block ----------------
__global__ __launch_bounds__(256, 2) void score_fused_kernel(const float* __restrict__ enc,
                                                             const short* __restrict__ wkb,
                                                             const float* __restrict__ qv,
                                                             const float* __restrict__ ven,
                                                             float* __restrict__ sp) {
    __shared__ __align__(16) short As[2][128 * 32];   // 2 x 8 KB
    __shared__ __align__(16) short Bs[2][256 * 32];   // 2 x 16 KB

    // XCD swizzle: 4 sibling N-tiles of a strip adjacent on one XCD -> enc L2 reuse
    const int bid    = blockIdx.x;
    const int xcd    = bid & 7;
    const int slot   = bid >> 3;                // 0..255
    const int mstrip = xcd * 64 + (slot >> 2);  // 0..511
    const int nt     = slot & 3;                // N quarter

    const int tid  = threadIdx.x;
    const int lane = tid & 63;
    const int wid  = tid >> 6;            // 0..3
    const int wr   = wid >> 1;            // 0..1  (M half)
    const int wc   = wid & 1;             // 0..1  (N half)
    const long mbase = (long)mstrip * 128;
    const int  nbase = nt * 256;

    f32x4 acc[4][8];
    #pragma unroll
    for (int m = 0; m < 4; ++m)
        #pragma unroll
        for (int n = 0; n < 8; ++n)
            acc[m][n] = (f32x4){0.f, 0.f, 0.f, 0.f};

    // ---- A staging: thread t -> row t>>1, k-half (t&1)*16 (16 consecutive f32)
    const int arow = tid >> 1;
    const float* ap = enc + (mbase + arow) * (long)HE + (tid & 1) * 16;
    const int aoff = arow * 32 + (tid & 1) * 16;   // shorts within As[buf]

    // ---- B staging: 1024 16B-chunks/K-step; thread covers c = j*256+tid, j=0..3.
    // chunk c -> B-row c>>2 (= j*64 + (tid>>2)), k-slot c&3 (= tid&3). LDS linear.
    const short* bp0 = wkb + (long)(nbase + (tid >> 2)) * HE + (tid & 3) * 8;
    const short* bp1 = bp0 + 64 * (long)HE;
    const short* bp2 = bp1 + 64 * (long)HE;
    const short* bp3 = bp2 + 64 * (long)HE;
    const int bd0 = (0 * 256 + wid * 64) * 16;     // LDS byte dest bases (+ lane*16)
    const int bd1 = (1 * 256 + wid * 64) * 16;
    const int bd2 = (2 * 256 + wid * 64) * 16;
    const int bd3 = (3 * 256 + wid * 64) * 16;

    const int frow = lane & 15;
    const int kby  = (lane >> 4) * 16;    // k-slot byte offset within 64B row

    #define BSTAGE(BUF, KT)                                  \
        do {                                                 \
            const int ko_ = (KT) * 32;                       \
            gload16(bp0 + ko_, (char*)Bs[BUF] + bd0);        \
            gload16(bp1 + ko_, (char*)Bs[BUF] + bd1);        \
            gload16(bp2 + ko_, (char*)Bs[BUF] + bd2);        \
            gload16(bp3 + ko_, (char*)Bs[BUF] + bd3);        \
        } while (0)

    #define ACOMMIT(BUF, R0, R1, R2, R3)                                     \
        do {                                                                 \
            bf16x8 w0_, w1_;                                                 \
            w0_[0]=f2bf(R0[0]); w0_[1]=f2bf(R0[1]); w0_[2]=f2bf(R0[2]); w0_[3]=f2bf(R0[3]); \
            w0_[4]=f2bf(R1[0]); w0_[5]=f2bf(R1[1]); w0_[6]=f2bf(R1[2]); w0_[7]=f2bf(R1[3]); \
            w1_[0]=f2bf(R2[0]); w1_[1]=f2bf(R2[1]); w1_[2]=f2bf(R2[2]); w1_[3]=f2bf(R2[3]); \
            w1_[4]=f2bf(R3[0]); w1_[5]=f2bf(R3[1]); w1_[6]=f2bf(R3[2]); w1_[7]=f2bf(R3[3]); \
            *(bf16x8*)((short*)As[BUF] + aoff)     = w0_;                    \
            *(bf16x8*)((short*)As[BUF] + aoff + 8) = w1_;                    \
        } while (0)

    #define COMPUTE(CUR)                                                     \
        do {                                                                 \
            bf16x8 af_[4], bf_[8];                                           \
            _Pragma("unroll")                                                \
            for (int m = 0; m < 4; ++m)                                      \
                af_[m] = *(const bf16x8*)((const char*)As[CUR]               \
                           + (wr * 64 + m * 16 + frow) * 64 + kby);          \
            _Pragma("unroll")                                                \
            for (int n = 0; n < 8; ++n)                                      \
                bf_[n] = *(const bf16x8*)((const char*)Bs[CUR]               \
                           + (wc * 128 + n * 16 + frow) * 64 + kby);         \
            _Pragma("unroll")                                                \
            for (int m = 0; m < 4; ++m)                                      \
                _Pragma("unroll")                                            \
                for (int n = 0; n < 8; ++n)                                  \
                    acc[m][n] = __builtin_amdgcn_mfma_f32_16x16x32_bf16(     \
                        af_[m], bf_[n], acc[m][n], 0, 0, 0);                 \
        } while (0)

    // ---- prologue: stage tile 0 ----
    {
        f32x4 a0 = *(const f32x4*)(ap + 0);
        f32x4 a1 = *(const f32x4*)(ap + 4);
        f32x4 a2 = *(const f32x4*)(ap + 8);
        f32x4 a3 = *(const f32x4*)(ap + 12);
        BSTAGE(0, 0);
        ACOMMIT(0, a0, a1, a2, a3);
        __syncthreads();
    }

    // ---- main loop: 2-phase, 1-deep prefetch (A via regs, B via gload_lds) ----
    for (int kt = 0; kt < NT; ++kt) {
        const int cur = kt & 1;
        f32x4 a0, a1, a2, a3;
        if (kt + 1 < NT) {
            const int ko = (kt + 1) * 32;
            a0 = *(const f32x4*)(ap + ko + 0);
            a1 = *(const f32x4*)(ap + ko + 4);
            a2 = *(const f32x4*)(ap + ko + 8);
            a3 = *(const f32x4*)(ap + ko + 12);
            BSTAGE(cur ^ 1, kt + 1);
        }
        COMPUTE(cur);
        if (kt + 1 < NT) {
            ACOMMIT(cur ^ 1, a0, a1, a2, a3);
            // drain next tile's staging + own LDS ops, then sync (fused asm:
            // nothing slips between wait and barrier). Other co-resident block
            // fills this CU's pipes during the drain.
            asm volatile("s_waitcnt vmcnt(0) lgkmcnt(0)\n\ts_barrier" ::: "memory");
        }
    }
    #undef COMPUTE
    #undef ACOMMIT
    #undef BSTAGE

    // ---- epilogue: partial score = sum over this wave's 128 cols of v[c]*tanh(q[b,c]+k)
    // C/D layout: col = lane&15 (N), row = (lane>>4)*4 + reg (M)
    const int bb = (int)(mbase >> 11);
    float qq[8], vv[8];
    #pragma unroll
    for (int n = 0; n < 8; ++n) {
        const int c = nbase + wc * 128 + n * 16 + frow;
        qq[n] = qv[bb * HD + c];
        vv[n] = ven[c];
    }
    float p[4][4];
    #pragma unroll
    for (int m = 0; m < 4; ++m) {
        #pragma unroll
        for (int rg = 0; rg < 4; ++rg) {
            float s = 0.f;
            #pragma unroll
            for (int n = 0; n < 8; ++n) {
                const float x = acc[m][n][rg] + qq[n];
                const float e = __expf(2.f * x);
                const float t = 1.f - 2.f * __builtin_amdgcn_rcpf(e + 1.f);
                s += vv[n] * t;
            }
            #pragma unroll
            for (int msk = 1; msk <= 8; msk <<= 1)
                s += __shfl_xor(s, msk, 64);   // reduce over 16-lane col group
            p[m][rg] = s;
        }
    }
    if ((lane & 15) == 0) {
        const int g = lane >> 4;
        float* dst = sp + (long)(nt * 2 + wc) * MM;   // 8 deterministic partial slots
        #pragma unroll
        for (int m = 0; m < 4; ++m)
            #pragma unroll
            for (int rg = 0; rg < 4; ++rg)
                dst[mbase + wr * 64 + m * 16 + g * 4 + rg] = p[m][rg];
    }
}

// ---------------- mask + softmax over S per batch ----------------
__global__ __launch_bounds__(256) void softmax_kernel(const float* __restrict__ sp,
                                                      const int* __restrict__ mask,
                                                      float* __restrict__ attn) {
    const int b = blockIdx.x;
    const int tid = threadIdx.x;
    const int lane = tid & 63;
    const int wid = tid >> 6;
    __shared__ float red[4];
    float sc[8];
    float mx = -3.0e38f;
    #pragma unroll
    for (int i = 0; i < 8; ++i) {
        const int s = tid + i * 256;
        float v = 0.f;
        #pragma unroll
        for (int k = 0; k < 8; ++k)
            v += sp[(long)k * MM + b * SS + s];
        if (mask[b * SS + s] == 0) v = -1e9f;
        sc[i] = v;
        mx = fmaxf(mx, v);
    }
    #pragma unroll
    for (int off = 32; off > 0; off >>= 1)
        mx = fmaxf(mx, __shfl_xor(mx, off, 64));
    if (lane == 0) red[wid] = mx;
    __syncthreads();
    mx = fmaxf(fmaxf(red[0], red[1]), fmaxf(red[2], red[3]));
    __syncthreads();
    float sum = 0.f;
    #pragma unroll
    for (int i = 0; i < 8; ++i) {
        const float e = __expf(sc[i] - mx);
        sc[i] = e;
        sum += e;
    }
    #pragma unroll
    for (int off = 32; off > 0; off >>= 1)
        sum += __shfl_xor(sum, off, 64);
    if (lane == 0) red[wid] = sum;
    __syncthreads();
    sum = red[0] + red[1] + red[2] + red[3];
    const float inv = 1.f / sum;
    #pragma unroll
    for (int i = 0; i < 8; ++i)
        attn[b * SS + tid + i * 256] = sc[i] * inv;
}

// ---------------- context: partial weighted sums over s-chunks (f32 enc) ----------------
__global__ __launch_bounds__(256) void ctx_partial_kernel(const float* __restrict__ enc,
                                                          const float* __restrict__ attn,
                                                          float* __restrict__ cp) {
    const int b = blockIdx.x >> 5;
    const int chunk = blockIdx.x & 31;
    const int tid = threadIdx.x;
    const float* ep = enc + ((long)b * SS + chunk * 64) * HE + tid * 4;
    const float* ap = attn + b * SS + chunk * 64;
    f32x4 acc = (f32x4){0.f, 0.f, 0.f, 0.f};
    #pragma unroll 4
    for (int s = 0; s < 64; ++s) {
        const float w = ap[s];
        const f32x4 v = *(const f32x4*)(ep + (long)s * HE);
        acc += w * v;
    }
    *(f32x4*)(cp + ((long)(b * 32 + chunk)) * HE + tid * 4) = acc;
}

__global__ __launch_bounds__(256) void ctx_reduce_kernel(const float* __restrict__ cp,
                                                         float* __restrict__ out) {
    const int o = blockIdx.x * 256 + threadIdx.x;
    const int b = o >> 10;
    const int e = o & 1023;
    float s = 0.f;
    #pragma unroll
    for (int c = 0; c < 32; ++c)
        s += cp[((long)(b * 32 + c)) * HE + e];
    out[o] = s;
}

extern "C" void kernel_launch(void* const* d_in, const int* in_sizes, int n_in,
                              void* d_out, int out_size, void* d_ws, size_t ws_size,
                              hipStream_t stream) {
    const float* dh   = (const float*)d_in[0];
    const float* enc  = (const float*)d_in[1];
    const int*   mask = (const int*)d_in[2];
    const float* Wq   = (const float*)d_in[3];
    const float* Wk   = (const float*)d_in[4];
    const float* Ve   = (const float*)d_in[5];

    float* out  = (float*)d_out;
    float* ctx  = out;
    float* attn = out + NB * HD;

    float* ws  = (float*)d_ws;
    float* wq_ = ws;                           // 32768 f
    float* sp  = ws + 32768;                   // 8 * 65536 f (2 MB)
    float* cp  = sp + 8 * (long)MM;            // 32*32*1024 f (4 MB)
    short* wkb = (short*)(cp + 32 * 32 * HE);  // 1M bf16 (2 MB)

    qproj_kernel<<<256, 256, 0, stream>>>(dh, Wq, wq_);
    cvt_bf16_kernel<<<512, 256, 0, stream>>>(Wk, wkb, HD * HE / 8);
    score_fused_kernel<<<2048, 256, 0, stream>>>(enc, wkb, wq_, Ve, sp);
    softmax_kernel<<<32, 256, 0, stream>>>(sp, mask, attn);
    ctx_partial_kernel<<<1024, 256, 0, stream>>>(enc, attn, cp);
    ctx_reduce_kernel<<<128, 256, 0, stream>>>(cp, ctx);
}

// Round 11
// 191.716 us; speedup vs baseline: 1.4709x; 1.4709x over previous
//
#include <hip/hip_runtime.h>
#include <hip/hip_bf16.h>

// Bahdanau attention (R11) = R9 score structure + MASK COMPACTION:
//   ~50% of rows are masked and provably contribute 0 to softmax/context
//   (exp(-1e9 - max) underflows to exactly 0 in f32). Compact unmasked rows
//   per batch (deterministic ballot scan), run the score GEMM only on them
//   (M_eff ~ 32768), and compute context only over them.
//   score GEMM: BM=128 x BN=512 x BK=32, 512 thr / 8 waves, acc[4][8],
//   enc rows gathered via idx (rows are 4KB contiguous -> coalesced),
//   B bf16 via global_load_lds, 2-deep A reg prefetch, counted vmcnt(2).

#define NB 32
#define SS 2048
#define HD 1024
#define HE 1024
#define MM (NB * SS)   // padded compacted row space
#define NT 32          // K-tiles = HE/32

typedef float f32x4 __attribute__((ext_vector_type(4)));
typedef short bf16x8 __attribute__((ext_vector_type(8)));
typedef short short4v __attribute__((ext_vector_type(4)));

static __device__ __forceinline__ short f2bf(float f) {
    union { __hip_bfloat16 h; short s; } u;
    u.h = __float2bfloat16(f);
    return u.s;
}

static __device__ __forceinline__ void gload16(const void* g, const void* l) {
    __builtin_amdgcn_global_load_lds(
        (const __attribute__((address_space(1))) void*)(uintptr_t)(g),
        (__attribute__((address_space(3))) void*)(unsigned)(uintptr_t)(l),
        16, 0, 0);
}

// ---------------- per-batch mask compaction: 1 wave per batch ----------------
__global__ __launch_bounds__(64) void compact_kernel(const int* __restrict__ mask,
                                                     int* __restrict__ idx,
                                                     int* __restrict__ cnt) {
    const int b = blockIdx.x;
    const int lane = threadIdx.x;
    int base = 0;
    for (int s0 = 0; s0 < SS; s0 += 64) {
        const int m = mask[b * SS + s0 + lane];
        const unsigned long long bal = __ballot(m != 0);
        const int rank = __popcll(bal & ((1ull << lane) - 1ull));
        if (m) idx[b * SS + base + rank] = s0 + lane;
        base += (int)__popcll(bal);
    }
    if (lane == 0) cnt[b] = base;
    for (int j = base + lane; j < SS; j += 64) idx[b * SS + j] = 0;  // safe pad
}

// ---------------- zero attn output region ----------------
__global__ __launch_bounds__(256) void zero_kernel(float* __restrict__ p, int n) {
    const int i = blockIdx.x * 256 + threadIdx.x;
    if (i < n) p[i] = 0.f;
}

// ---------------- f32 -> bf16 conversion (Wk only) ----------------
__global__ __launch_bounds__(256) void cvt_bf16_kernel(const float* __restrict__ in,
                                                       short* __restrict__ out, int n8) {
    int i = blockIdx.x * 256 + threadIdx.x;
    const int stride = gridDim.x * 256;
    for (; i < n8; i += stride) {
        const f32x4 a = *(const f32x4*)(in + (long)i * 8);
        const f32x4 b = *(const f32x4*)(in + (long)i * 8 + 4);
        bf16x8 o;
        o[0] = f2bf(a[0]); o[1] = f2bf(a[1]); o[2] = f2bf(a[2]); o[3] = f2bf(a[3]);
        o[4] = f2bf(b[0]); o[5] = f2bf(b[1]); o[6] = f2bf(b[2]); o[7] = f2bf(b[3]);
        *(bf16x8*)(out + (long)i * 8) = o;
    }
}

// ---------------- q = dh @ Wq^T ----------------
__global__ __launch_bounds__(256) void qproj_kernel(const float* __restrict__ dh,
                                                    const float* __restrict__ Wq,
                                                    float* __restrict__ q) {
    const int wid  = threadIdx.x >> 6;
    const int lane = threadIdx.x & 63;
    const int d    = blockIdx.x * 4 + wid;
    const float* wrow = Wq + (long)d * HD + lane * 16;
    f32x4 w0 = *(const f32x4*)(wrow + 0);
    f32x4 w1 = *(const f32x4*)(wrow + 4);
    f32x4 w2 = *(const f32x4*)(wrow + 8);
    f32x4 w3 = *(const f32x4*)(wrow + 12);
    for (int b = 0; b < NB; ++b) {
        const float* drow = dh + b * HD + lane * 16;
        f32x4 d0 = *(const f32x4*)(drow + 0);
        f32x4 d1 = *(const f32x4*)(drow + 4);
        f32x4 d2 = *(const f32x4*)(drow + 8);
        f32x4 d3 = *(const f32x4*)(drow + 12);
        f32x4 s4 = w0 * d0 + w1 * d1 + w2 * d2 + w3 * d3;
        float dot = s4[0] + s4[1] + s4[2] + s4[3];
        #pragma unroll
        for (int off = 32; off > 0; off >>= 1)
            dot += __shfl_xor(dot, off, 64);
        if (lane == 0) q[b * HD + d] = dot;
    }
}

// ---------------- fused score GEMM on COMPACTED rows (R9 structure) ----------------
__global__ __launch_bounds__(512, 2) void score_fused_kernel(const float* __restrict__ enc,
                                                             const short* __restrict__ wkb,
                                                             const float* __restrict__ qv,
                                                             const float* __restrict__ ven,
                                                             const int* __restrict__ idx,
                                                             const int* __restrict__ cnt,
                                                             float* __restrict__ sp) {
    __shared__ __align__(16) short As[2][128 * 32];   // 2 x 8 KB
    __shared__ __align__(16) short Bs[2][512 * 32];   // 2 x 32 KB

    const int bid    = blockIdx.x;
    const int xcd    = bid & 7;
    const int slot   = bid >> 3;               // 0..127
    const int mstrip = xcd * 64 + (slot >> 1); // 0..511 = b*16 + tile
    const int nt     = slot & 1;               // N half
    const int bb     = mstrip >> 4;            // batch
    const int tile   = mstrip & 15;            // 128-row tile within batch

    if (tile * 128 >= cnt[bb]) return;         // fully-masked tail tile: dead

    const int tid  = threadIdx.x;
    const int lane = tid & 63;
    const int wid  = tid >> 6;
    const int wr   = wid >> 2;
    const int wc   = wid & 3;
    const long mbase = (long)bb * SS + tile * 128;   // padded compacted row base
    const int  nbase = nt * 512;

    f32x4 acc[4][8];
    #pragma unroll
    for (int m = 0; m < 4; ++m)
        #pragma unroll
        for (int n = 0; n < 8; ++n)
            acc[m][n] = (f32x4){0.f, 0.f, 0.f, 0.f};

    // ---- A staging with row indirection: thread t -> compacted rows r, r+64
    const int arow = tid >> 3;
    const int r0i = idx[mbase + arow];         // actual s within batch
    const int r1i = idx[mbase + arow + 64];
    const float* ap0 = enc + ((long)bb * SS + r0i) * HE + (tid & 7) * 4;
    const float* ap1 = enc + ((long)bb * SS + r1i) * HE + (tid & 7) * 4;
    const int as_  = (arow & 3) ^ ((arow >> 2) & 3);
    const int awb  = (((tid & 7) >> 1) ^ as_) * 16 + (tid & 1) * 8;
    const int aw0  = arow * 64 + awb;
    const int aw1  = (arow + 64) * 64 + awb;

    // ---- B staging (pre-swizzled source, linear LDS dest)
    const int bswz = ((tid & 3) ^ ((tid >> 2) & 3) ^ ((tid >> 4) & 3)) * 8;
    const short* bp0 = wkb + (long)(nbase + (tid >> 2)) * HE + bswz;
    const short* bp1 = bp0 + 128 * (long)HE;
    const short* bp2 = bp1 + 128 * (long)HE;
    const short* bp3 = bp2 + 128 * (long)HE;
    const int bd0 = (0 * 512 + wid * 64) * 16;
    const int bd1 = (1 * 512 + wid * 64) * 16;
    const int bd2 = (2 * 512 + wid * 64) * 16;
    const int bd3 = (3 * 512 + wid * 64) * 16;

    const int frow = lane & 15;
    const int kby  = (((lane >> 4) ^ (frow & 3) ^ ((frow >> 2) & 3))) * 16;

    #define BSTAGE(BUF, KT)                                  \
        do {                                                 \
            const int ko_ = (KT) * 32;                       \
            gload16(bp0 + ko_, (char*)Bs[BUF] + bd0);        \
            gload16(bp1 + ko_, (char*)Bs[BUF] + bd1);        \
            gload16(bp2 + ko_, (char*)Bs[BUF] + bd2);        \
            gload16(bp3 + ko_, (char*)Bs[BUF] + bd3);        \
        } while (0)

    #define ACOMMIT(BUF, RA, RB)                                             \
        do {                                                                 \
            short4v v0_, v1_;                                                \
            v0_[0]=f2bf(RA[0]); v0_[1]=f2bf(RA[1]); v0_[2]=f2bf(RA[2]); v0_[3]=f2bf(RA[3]); \
            v1_[0]=f2bf(RB[0]); v1_[1]=f2bf(RB[1]); v1_[2]=f2bf(RB[2]); v1_[3]=f2bf(RB[3]); \
            *(short4v*)((char*)As[BUF] + aw0) = v0_;                         \
            *(short4v*)((char*)As[BUF] + aw1) = v1_;                         \
        } while (0)

    #define COMPUTE(CUR)                                                     \
        do {                                                                 \
            bf16x8 af_[4], bf_[8];                                           \
            _Pragma("unroll")                                                \
            for (int m = 0; m < 4; ++m)                                      \
                af_[m] = *(const bf16x8*)((const char*)As[CUR]               \
                           + (wr * 64 + m * 16 + frow) * 64 + kby);          \
            _Pragma("unroll")                                                \
            for (int n = 0; n < 8; ++n)                                      \
                bf_[n] = *(const bf16x8*)((const char*)Bs[CUR]               \
                           + (wc * 128 + n * 16 + frow) * 64 + kby);         \
            _Pragma("unroll")                                                \
            for (int m = 0; m < 4; ++m)                                      \
                _Pragma("unroll")                                            \
                for (int n = 0; n < 8; ++n)                                  \
                    acc[m][n] = __builtin_amdgcn_mfma_f32_16x16x32_bf16(     \
                        af_[m], bf_[n], acc[m][n], 0, 0, 0);                 \
        } while (0)

    #define PHASE_S(CUR, KT, AH0, AH1, AF0, AF1)                             \
        do {                                                                 \
            BSTAGE((CUR) ^ 1, (KT) + 1);                                     \
            AF0 = *(const f32x4*)(ap0 + ((KT) + 2) * 32);                    \
            AF1 = *(const f32x4*)(ap1 + ((KT) + 2) * 32);                    \
            COMPUTE(CUR);                                                    \
            ACOMMIT((CUR) ^ 1, AH0, AH1);                                    \
            asm volatile("s_waitcnt vmcnt(2) lgkmcnt(0)\n\ts_barrier" ::: "memory"); \
        } while (0)

    // ---- prologue ----
    f32x4 aE0, aE1, aO0, aO1;
    {
        BSTAGE(0, 0);
        f32x4 p0 = *(const f32x4*)(ap0);
        f32x4 p1 = *(const f32x4*)(ap1);
        ACOMMIT(0, p0, p1);
        aE0 = *(const f32x4*)(ap0 + 32);
        aE1 = *(const f32x4*)(ap1 + 32);
        asm volatile("s_waitcnt lgkmcnt(0)\n\ts_barrier" ::: "memory");
    }

    for (int kt = 0; kt < NT - 4; kt += 2) {
        PHASE_S(0, kt,     aE0, aE1, aO0, aO1);
        PHASE_S(1, kt + 1, aO0, aO1, aE0, aE1);
    }
    PHASE_S(0, NT - 4, aE0, aE1, aO0, aO1);
    PHASE_S(1, NT - 3, aO0, aO1, aE0, aE1);
    {
        BSTAGE(1, NT - 1);
        COMPUTE(0);
        ACOMMIT(1, aE0, aE1);
        asm volatile("s_waitcnt vmcnt(0) lgkmcnt(0)\n\ts_barrier" ::: "memory");
    }
    COMPUTE(1);
    #undef PHASE_S
    #undef COMPUTE
    #undef ACOMMIT
    #undef BSTAGE

    // ---- epilogue ----
    float qq[8], vv[8];
    #pragma unroll
    for (int n = 0; n < 8; ++n) {
        const int c = nbase + wc * 128 + n * 16 + frow;
        qq[n] = qv[bb * HD + c];
        vv[n] = ven[c];
    }
    float p[4][4];
    #pragma unroll
    for (int m = 0; m < 4; ++m) {
        #pragma unroll
        for (int rg = 0; rg < 4; ++rg) {
            float s = 0.f;
            #pragma unroll
            for (int n = 0; n < 8; ++n) {
                const float x = acc[m][n][rg] + qq[n];
                const float e = __expf(2.f * x);
                const float t = 1.f - 2.f * __builtin_amdgcn_rcpf(e + 1.f);
                s += vv[n] * t;
            }
            #pragma unroll
            for (int msk = 1; msk <= 8; msk <<= 1)
                s += __shfl_xor(s, msk, 64);
            p[m][rg] = s;
        }
    }
    if ((lane & 15) == 0) {
        const int g = lane >> 4;
        float* dst = sp + (long)(nt * 4 + wc) * MM;
        #pragma unroll
        for (int m = 0; m < 4; ++m)
            #pragma unroll
            for (int rg = 0; rg < 4; ++rg)
                dst[mbase + wr * 64 + m * 16 + g * 4 + rg] = p[m][rg];
    }
}

// ---------------- softmax over compacted domain; scatter to attn ----------------
__global__ __launch_bounds__(256) void softmax_kernel(const float* __restrict__ sp,
                                                      const int* __restrict__ idx,
                                                      const int* __restrict__ cnt,
                                                      float* __restrict__ attn,
                                                      float* __restrict__ wcomp) {
    const int b = blockIdx.x;
    const int tid = threadIdx.x;
    const int lane = tid & 63;
    const int wid = tid >> 6;
    const int n = cnt[b];
    __shared__ float red[4];
    float sc[8];
    float mx = -3.0e38f;
    #pragma unroll
    for (int i = 0; i < 8; ++i) {
        const int j = tid + i * 256;
        float v = -3.0e38f;
        if (j < n) {
            v = 0.f;
            #pragma unroll
            for (int k = 0; k < 8; ++k)
                v += sp[(long)k * MM + b * SS + j];
        }
        sc[i] = v;
        mx = fmaxf(mx, v);
    }
    #pragma unroll
    for (int off = 32; off > 0; off >>= 1)
        mx = fmaxf(mx, __shfl_xor(mx, off, 64));
    if (lane == 0) red[wid] = mx;
    __syncthreads();
    mx = fmaxf(fmaxf(red[0], red[1]), fmaxf(red[2], red[3]));
    __syncthreads();
    float sum = 0.f;
    #pragma unroll
    for (int i = 0; i < 8; ++i) {
        const float e = (sc[i] > -1.0e38f) ? __expf(sc[i] - mx) : 0.f;
        sc[i] = e;
        sum += e;
    }
    #pragma unroll
    for (int off = 32; off > 0; off >>= 1)
        sum += __shfl_xor(sum, off, 64);
    if (lane == 0) red[wid] = sum;
    __syncthreads();
    sum = red[0] + red[1] + red[2] + red[3];
    const float inv = 1.f / sum;
    #pragma unroll
    for (int i = 0; i < 8; ++i) {
        const int j = tid + i * 256;
        const float w = sc[i] * inv;
        wcomp[b * SS + j] = w;                    // 0 beyond cnt (sc=0 there)
        if (j < n) attn[b * SS + idx[b * SS + j]] = w;
    }
}

// ---------------- context over compacted rows ----------------
__global__ __launch_bounds__(256) void ctx_partial_kernel(const float* __restrict__ enc,
                                                          const float* __restrict__ wcomp,
                                                          const int* __restrict__ idx,
                                                          const int* __restrict__ cnt,
                                                          float* __restrict__ cp) {
    const int b = blockIdx.x >> 5;
    const int chunk = blockIdx.x & 31;
    const int tid = threadIdx.x;
    float* dst = cp + ((long)(b * 32 + chunk)) * HE + tid * 4;
    if (chunk * 64 >= cnt[b]) {                 // dead chunk: zero its partial
        *(f32x4*)dst = (f32x4){0.f, 0.f, 0.f, 0.f};
        return;
    }
    f32x4 acc = (f32x4){0.f, 0.f, 0.f, 0.f};
    #pragma unroll 4
    for (int s = 0; s < 64; ++s) {
        const int j = chunk * 64 + s;
        const float w = wcomp[b * SS + j];      // exact 0 for padding
        const int row = idx[b * SS + j];
        const f32x4 v = *(const f32x4*)(enc + ((long)b * SS + row) * HE + tid * 4);
        acc += w * v;
    }
    *(f32x4*)dst = acc;
}

__global__ __launch_bounds__(256) void ctx_reduce_kernel(const float* __restrict__ cp,
                                                         float* __restrict__ out) {
    const int o = blockIdx.x * 256 + threadIdx.x;
    const int b = o >> 10;
    const int e = o & 1023;
    float s = 0.f;
    #pragma unroll
    for (int c = 0; c < 32; ++c)
        s += cp[((long)(b * 32 + c)) * HE + e];
    out[o] = s;
}

extern "C" void kernel_launch(void* const* d_in, const int* in_sizes, int n_in,
                              void* d_out, int out_size, void* d_ws, size_t ws_size,
                              hipStream_t stream) {
    const float* dh   = (const float*)d_in[0];
    const float* enc  = (const float*)d_in[1];
    const int*   mask = (const int*)d_in[2];
    const float* Wq   = (const float*)d_in[3];
    const float* Wk   = (const float*)d_in[4];
    const float* Ve   = (const float*)d_in[5];

    float* out  = (float*)d_out;
    float* ctx  = out;
    float* attn = out + NB * HD;

    float* ws    = (float*)d_ws;
    float* wq_   = ws;                            // 32768 f
    float* sp    = ws + 32768;                    // 8 * 65536 f (2 MB)
    float* cp    = sp + 8 * (long)MM;             // 32*32*1024 f (4 MB)
    short* wkb   = (short*)(cp + 32 * 32 * HE);   // 1M bf16 (2 MB)
    float* wcomp = (float*)(wkb + (long)HD * HE); // 65536 f
    int*   idx   = (int*)(wcomp + MM);            // 65536 i
    int*   cnt   = idx + MM;                      // 32 i

    compact_kernel<<<NB, 64, 0, stream>>>(mask, idx, cnt);
    zero_kernel<<<MM / 256, 256, 0, stream>>>(attn, MM);
    qproj_kernel<<<256, 256, 0, stream>>>(dh, Wq, wq_);
    cvt_bf16_kernel<<<512, 256, 0, stream>>>(Wk, wkb, HD * HE / 8);
    score_fused_kernel<<<1024, 512, 0, stream>>>(enc, wkb, wq_, Ve, idx, cnt, sp);
    softmax_kernel<<<NB, 256, 0, stream>>>(sp, idx, cnt, attn, wcomp);
    ctx_partial_kernel<<<1024, 256, 0, stream>>>(enc, wcomp, idx, cnt, cp);
    ctx_reduce_kernel<<<128, 256, 0, stream>>>(cp, ctx);
}

// Round 12
// 187.568 us; speedup vs baseline: 1.5035x; 1.0221x over previous
//
#include <hip/hip_runtime.h>
#include <hip/hip_bf16.h>

// Bahdanau attention (R12) = mask compaction (R11) + compacted-bf16 pre-pass +
// R2/m97-style GEMM (128x128 tile, 4 waves, acc[4][4] -> ~2.4 blocks/CU).
//   compact: per-batch ballot scan -> idx/cnt (~50% rows unmasked)
//   cvt_enc: gather unmasked rows -> compacted bf16 encb, pad to 128 with zeros
//   score:   v . tanh(q + Wk @ enc_row) on compacted rows only, pure bf16 GEMM,
//            both A and B via global_load_lds, XCD swizzle (8 sibling N-tiles/XCD)
//   softmax over compacted domain, scatter weights; ctx over compacted bf16 rows.

#define NB 32
#define SS 2048
#define HD 1024
#define HE 1024
#define MM (NB * SS)   // compacted (padded) row space
#define NT 32          // K-tiles = HE/32

typedef float f32x4 __attribute__((ext_vector_type(4)));
typedef short bf16x8 __attribute__((ext_vector_type(8)));
typedef short short4v __attribute__((ext_vector_type(4)));

static __device__ __forceinline__ short f2bf(float f) {
    union { __hip_bfloat16 h; short s; } u;
    u.h = __float2bfloat16(f);
    return u.s;
}
static __device__ __forceinline__ float bf2f(short s) {
    union { float f; unsigned u; } u;
    u.u = ((unsigned)(unsigned short)s) << 16;
    return u.f;
}

static __device__ __forceinline__ void gload16(const void* g, const void* l) {
    __builtin_amdgcn_global_load_lds(
        (const __attribute__((address_space(1))) void*)(uintptr_t)(g),
        (__attribute__((address_space(3))) void*)(unsigned)(uintptr_t)(l),
        16, 0, 0);
}

// ---------------- per-batch mask compaction: 1 wave per batch ----------------
__global__ __launch_bounds__(64) void compact_kernel(const int* __restrict__ mask,
                                                     int* __restrict__ idx,
                                                     int* __restrict__ cnt) {
    const int b = blockIdx.x;
    const int lane = threadIdx.x;
    int base = 0;
    for (int s0 = 0; s0 < SS; s0 += 64) {
        const int m = mask[b * SS + s0 + lane];
        const unsigned long long bal = __ballot(m != 0);
        const int rank = __popcll(bal & ((1ull << lane) - 1ull));
        if (m) idx[b * SS + base + rank] = s0 + lane;
        base += (int)__popcll(bal);
    }
    if (lane == 0) cnt[b] = base;
    for (int j = base + lane; j < SS; j += 64) idx[b * SS + j] = 0;
}

__global__ __launch_bounds__(256) void zero_kernel(float* __restrict__ p, int n) {
    const int i = blockIdx.x * 256 + threadIdx.x;
    if (i < n) p[i] = 0.f;
}

// ---------------- f32 -> bf16 (Wk) ----------------
__global__ __launch_bounds__(256) void cvt_bf16_kernel(const float* __restrict__ in,
                                                       short* __restrict__ out, int n8) {
    int i = blockIdx.x * 256 + threadIdx.x;
    const int stride = gridDim.x * 256;
    for (; i < n8; i += stride) {
        const f32x4 a = *(const f32x4*)(in + (long)i * 8);
        const f32x4 b = *(const f32x4*)(in + (long)i * 8 + 4);
        bf16x8 o;
        o[0] = f2bf(a[0]); o[1] = f2bf(a[1]); o[2] = f2bf(a[2]); o[3] = f2bf(a[3]);
        o[4] = f2bf(b[0]); o[5] = f2bf(b[1]); o[6] = f2bf(b[2]); o[7] = f2bf(b[3]);
        *(bf16x8*)(out + (long)i * 8) = o;
    }
}

// ---------------- gather + cvt enc rows -> compacted bf16, zero-pad to 128 ----------------
// block: 16 compacted rows of one batch; thread t -> row j0+(t>>4), col lane (t&15).
// per u: 8 f32 at col (t&15)*8 + u*128 (coalesced 512B per 16-lane group).
__global__ __launch_bounds__(256) void cvt_enc_kernel(const float* __restrict__ enc,
                                                      const int* __restrict__ idx,
                                                      const int* __restrict__ cnt,
                                                      short* __restrict__ encb) {
    const int b  = blockIdx.x >> 7;
    const int j0 = (blockIdx.x & 127) * 16;
    const int n  = cnt[b];
    const int nr = (n + 127) & ~127;
    if (j0 >= nr) return;
    const int j  = j0 + (threadIdx.x >> 4);
    const int c0 = (threadIdx.x & 15) * 8;
    short* dst = encb + ((long)b * SS + j) * HE + c0;
    if (j < n) {
        const float* src = enc + ((long)b * SS + idx[b * SS + j]) * HE + c0;
        #pragma unroll
        for (int u = 0; u < 8; ++u) {
            const f32x4 x = *(const f32x4*)(src + u * 128);
            const f32x4 y = *(const f32x4*)(src + u * 128 + 4);
            bf16x8 o;
            o[0] = f2bf(x[0]); o[1] = f2bf(x[1]); o[2] = f2bf(x[2]); o[3] = f2bf(x[3]);
            o[4] = f2bf(y[0]); o[5] = f2bf(y[1]); o[6] = f2bf(y[2]); o[7] = f2bf(y[3]);
            *(bf16x8*)(dst + u * 128) = o;
        }
    } else {
        const bf16x8 z = (bf16x8){0,0,0,0,0,0,0,0};
        #pragma unroll
        for (int u = 0; u < 8; ++u) *(bf16x8*)(dst + u * 128) = z;
    }
}

// ---------------- q = dh @ Wq^T ----------------
__global__ __launch_bounds__(256) void qproj_kernel(const float* __restrict__ dh,
                                                    const float* __restrict__ Wq,
                                                    float* __restrict__ q) {
    const int wid  = threadIdx.x >> 6;
    const int lane = threadIdx.x & 63;
    const int d    = blockIdx.x * 4 + wid;
    const float* wrow = Wq + (long)d * HD + lane * 16;
    f32x4 w0 = *(const f32x4*)(wrow + 0);
    f32x4 w1 = *(const f32x4*)(wrow + 4);
    f32x4 w2 = *(const f32x4*)(wrow + 8);
    f32x4 w3 = *(const f32x4*)(wrow + 12);
    for (int b = 0; b < NB; ++b) {
        const float* drow = dh + b * HD + lane * 16;
        f32x4 d0 = *(const f32x4*)(drow + 0);
        f32x4 d1 = *(const f32x4*)(drow + 4);
        f32x4 d2 = *(const f32x4*)(drow + 8);
        f32x4 d3 = *(const f32x4*)(drow + 12);
        f32x4 s4 = w0 * d0 + w1 * d1 + w2 * d2 + w3 * d3;
        float dot = s4[0] + s4[1] + s4[2] + s4[3];
        #pragma unroll
        for (int off = 32; off > 0; off >>= 1)
            dot += __shfl_xor(dot, off, 64);
        if (lane == 0) q[b * HD + d] = dot;
    }
}

// ---------------- R2/m97-style score GEMM on compacted bf16 rows ----------------
// 128x128 tile, 4 waves (2x2 of 64x64), acc[4][4]; A=encb, B=wkb via global_load_lds.
__global__ __launch_bounds__(256, 3) void score_mfma_kernel(const short* __restrict__ encb,
                                                            const short* __restrict__ wkb,
                                                            const float* __restrict__ qv,
                                                            const float* __restrict__ ven,
                                                            const int* __restrict__ cnt,
                                                            float* __restrict__ sp) {
    __shared__ __align__(16) short As[4096];   // [128][32] bf16, 8 KB
    __shared__ __align__(16) short Bs[4096];

    // XCD swizzle: 8 sibling N-tiles of an M-tile on one XCD (A L2 reuse)
    const int bid   = blockIdx.x;
    const int xcd   = bid & 7;
    const int slot  = bid >> 3;                 // 0..511
    const int mtile = xcd * 64 + (slot >> 3);   // 0..511
    const int nt    = slot & 7;                 // 0..7

    const int bb   = mtile >> 4;
    const int tile = mtile & 15;
    if (tile * 128 >= cnt[bb]) return;          // masked tail tile: dead

    const int tid  = threadIdx.x;
    const int lane = tid & 63;
    const int wid  = tid >> 6;
    const int wr   = wid >> 1;
    const int wc   = wid & 1;
    const long mbase = (long)bb * SS + tile * 128;   // compacted row base
    const int  nbase = nt * 128;

    f32x4 acc[4][4];
    #pragma unroll
    for (int m = 0; m < 4; ++m)
        #pragma unroll
        for (int n = 0; n < 4; ++n)
            acc[m][n] = (f32x4){0.f, 0.f, 0.f, 0.f};

    // staging: chunk c = tid, tid+256 -> row c>>2, k-slot c&3
    const short* ag0 = encb + (mbase + (tid >> 2)) * (long)HE + (tid & 3) * 8;
    const short* ag1 = ag0 + 64 * (long)HE;
    const short* bg0 = wkb + ((long)(nbase + (tid >> 2))) * HE + (tid & 3) * 8;
    const short* bg1 = bg0 + 64 * (long)HE;

    const int frow = lane & 15;
    const int kby  = (lane >> 4) * 16;

    for (int kt = 0; kt < NT; ++kt) {
        const int ko = kt * 32;
        gload16(ag0 + ko, (char*)As + wid * 1024);
        gload16(ag1 + ko, (char*)As + 4096 + wid * 1024);
        gload16(bg0 + ko, (char*)Bs + wid * 1024);
        gload16(bg1 + ko, (char*)Bs + 4096 + wid * 1024);
        __syncthreads();   // drains vmcnt (gload_lds complete) + joins waves

        bf16x8 af[4], bfr[4];
        #pragma unroll
        for (int m = 0; m < 4; ++m)
            af[m] = *(const bf16x8*)((const char*)As + (wr * 64 + m * 16 + frow) * 64 + kby);
        #pragma unroll
        for (int n = 0; n < 4; ++n)
            bfr[n] = *(const bf16x8*)((const char*)Bs + (wc * 64 + n * 16 + frow) * 64 + kby);
        #pragma unroll
        for (int m = 0; m < 4; ++m)
            #pragma unroll
            for (int n = 0; n < 4; ++n)
                acc[m][n] = __builtin_amdgcn_mfma_f32_16x16x32_bf16(af[m], bfr[n], acc[m][n], 0, 0, 0);
        __syncthreads();   // LDS reads done before next iter overwrites
    }

    // epilogue: partial score over this wave's 64 cols; C/D: col=lane&15, row=(lane>>4)*4+reg
    float qq[4], vv[4];
    #pragma unroll
    for (int n = 0; n < 4; ++n) {
        const int c = nbase + wc * 64 + n * 16 + frow;
        qq[n] = qv[bb * HD + c];
        vv[n] = ven[c];
    }
    float p[4][4];
    #pragma unroll
    for (int m = 0; m < 4; ++m) {
        #pragma unroll
        for (int rg = 0; rg < 4; ++rg) {
            float s = 0.f;
            #pragma unroll
            for (int n = 0; n < 4; ++n) {
                const float x = acc[m][n][rg] + qq[n];
                const float e = __expf(2.f * x);
                const float t = 1.f - 2.f * __builtin_amdgcn_rcpf(e + 1.f);
                s += vv[n] * t;
            }
            #pragma unroll
            for (int msk = 1; msk <= 8; msk <<= 1)
                s += __shfl_xor(s, msk, 64);
            p[m][rg] = s;
        }
    }
    if ((lane & 15) == 0) {
        const int g = lane >> 4;
        float* dst = sp + (long)(nt * 2 + wc) * MM;   // 16 deterministic partial slots
        #pragma unroll
        for (int m = 0; m < 4; ++m)
            #pragma unroll
            for (int rg = 0; rg < 4; ++rg)
                dst[mbase + wr * 64 + m * 16 + g * 4 + rg] = p[m][rg];
    }
}

// ---------------- softmax over compacted domain; scatter to attn ----------------
__global__ __launch_bounds__(256) void softmax_kernel(const float* __restrict__ sp,
                                                      const int* __restrict__ idx,
                                                      const int* __restrict__ cnt,
                                                      float* __restrict__ attn,
                                                      float* __restrict__ wcomp) {
    const int b = blockIdx.x;
    const int tid = threadIdx.x;
    const int lane = tid & 63;
    const int wid = tid >> 6;
    const int n = cnt[b];
    __shared__ float red[4];
    float sc[8];
    float mx = -3.0e38f;
    #pragma unroll
    for (int i = 0; i < 8; ++i) {
        const int j = tid + i * 256;
        float v = -3.0e38f;
        if (j < n) {
            v = 0.f;
            #pragma unroll
            for (int k = 0; k < 16; ++k)
                v += sp[(long)k * MM + b * SS + j];
        }
        sc[i] = v;
        mx = fmaxf(mx, v);
    }
    #pragma unroll
    for (int off = 32; off > 0; off >>= 1)
        mx = fmaxf(mx, __shfl_xor(mx, off, 64));
    if (lane == 0) red[wid] = mx;
    __syncthreads();
    mx = fmaxf(fmaxf(red[0], red[1]), fmaxf(red[2], red[3]));
    __syncthreads();
    float sum = 0.f;
    #pragma unroll
    for (int i = 0; i < 8; ++i) {
        const float e = (sc[i] > -1.0e38f) ? __expf(sc[i] - mx) : 0.f;
        sc[i] = e;
        sum += e;
    }
    #pragma unroll
    for (int off = 32; off > 0; off >>= 1)
        sum += __shfl_xor(sum, off, 64);
    if (lane == 0) red[wid] = sum;
    __syncthreads();
    sum = red[0] + red[1] + red[2] + red[3];
    const float inv = 1.f / sum;
    #pragma unroll
    for (int i = 0; i < 8; ++i) {
        const int j = tid + i * 256;
        const float w = sc[i] * inv;
        wcomp[b * SS + j] = w;                    // exact 0 beyond cnt
        if (j < n) attn[b * SS + idx[b * SS + j]] = w;
    }
}

// ---------------- context over compacted bf16 rows (no indirection) ----------------
__global__ __launch_bounds__(256) void ctx_partial_kernel(const short* __restrict__ encb,
                                                          const float* __restrict__ wcomp,
                                                          const int* __restrict__ cnt,
                                                          float* __restrict__ cp) {
    const int b = blockIdx.x >> 5;
    const int chunk = blockIdx.x & 31;
    const int tid = threadIdx.x;
    float* dst = cp + ((long)(b * 32 + chunk)) * HE + tid * 4;
    if (chunk * 64 >= cnt[b]) {
        *(f32x4*)dst = (f32x4){0.f, 0.f, 0.f, 0.f};
        return;
    }
    const short* ep = encb + ((long)b * SS + chunk * 64) * HE + tid * 4;
    const float* ap = wcomp + b * SS + chunk * 64;
    f32x4 acc = (f32x4){0.f, 0.f, 0.f, 0.f};
    #pragma unroll 4
    for (int s = 0; s < 64; ++s) {
        const float w = ap[s];                  // 0 in pad zone; pad rows are zero too
        const short4v v = *(const short4v*)(ep + (long)s * HE);
        acc[0] += w * bf2f(v[0]);
        acc[1] += w * bf2f(v[1]);
        acc[2] += w * bf2f(v[2]);
        acc[3] += w * bf2f(v[3]);
    }
    *(f32x4*)dst = acc;
}

__global__ __launch_bounds__(256) void ctx_reduce_kernel(const float* __restrict__ cp,
                                                         float* __restrict__ out) {
    const int o = blockIdx.x * 256 + threadIdx.x;
    const int b = o >> 10;
    const int e = o & 1023;
    float s = 0.f;
    #pragma unroll
    for (int c = 0; c < 32; ++c)
        s += cp[((long)(b * 32 + c)) * HE + e];
    out[o] = s;
}

extern "C" void kernel_launch(void* const* d_in, const int* in_sizes, int n_in,
                              void* d_out, int out_size, void* d_ws, size_t ws_size,
                              hipStream_t stream) {
    const float* dh   = (const float*)d_in[0];
    const float* enc  = (const float*)d_in[1];
    const int*   mask = (const int*)d_in[2];
    const float* Wq   = (const float*)d_in[3];
    const float* Wk   = (const float*)d_in[4];
    const float* Ve   = (const float*)d_in[5];

    float* out  = (float*)d_out;
    float* ctx  = out;
    float* attn = out + NB * HD;

    float* ws    = (float*)d_ws;
    float* wq_   = ws;                            // 32768 f
    float* sp    = ws + 32768;                    // 16 * 65536 f (4 MB)
    float* cp    = sp + 16 * (long)MM;            // 32*32*1024 f (4 MB)
    short* wkb   = (short*)(cp + 32 * 32 * HE);   // 1M bf16 (2 MB)
    float* wcomp = (float*)(wkb + (long)HD * HE); // 65536 f
    int*   idx   = (int*)(wcomp + MM);            // 65536 i
    int*   cnt   = idx + MM;                      // 32 i (+pad)
    short* encb  = (short*)(cnt + 64);            // 67.1M bf16 (128 MB)

    compact_kernel<<<NB, 64, 0, stream>>>(mask, idx, cnt);
    zero_kernel<<<MM / 256, 256, 0, stream>>>(attn, MM);
    qproj_kernel<<<256, 256, 0, stream>>>(dh, Wq, wq_);
    cvt_bf16_kernel<<<512, 256, 0, stream>>>(Wk, wkb, HD * HE / 8);
    cvt_enc_kernel<<<NB * 128, 256, 0, stream>>>(enc, idx, cnt, encb);
    score_mfma_kernel<<<4096, 256, 0, stream>>>(encb, wkb, wq_, Ve, cnt, sp);
    softmax_kernel<<<NB, 256, 0, stream>>>(sp, idx, cnt, attn, wcomp);
    ctx_partial_kernel<<<1024, 256, 0, stream>>>(encb, wcomp, cnt, cp);
    ctx_reduce_kernel<<<128, 256, 0, stream>>>(cp, ctx);
}

// Round 13
// 181.758 us; speedup vs baseline: 1.5515x; 1.0320x over previous
//
#include <hip/hip_runtime.h>
#include <hip/hip_bf16.h>

// Bahdanau attention (R13) = R12 + two K-tiles per barrier epoch (16 epochs not 32)
// + attn zeroing folded into softmax.
//   compact: per-batch ballot scan -> idx/cnt (~50% rows unmasked)
//   cvt_enc: gather unmasked rows -> compacted bf16 encb (zero-pad to 128)
//   score:   m97-style 128x128 bf16 GEMM over compacted rows, 4 waves, acc[4][4],
//            A+B via global_load_lds, 2 K-tiles staged per sync epoch (32KB LDS),
//            XCD swizzle (8 sibling N-tiles/XCD), fused tanh/v-dot epilogue
//   softmax over compacted domain (dense-zeroes attn, then scatters weights)
//   ctx over compacted bf16 rows.

#define NB 32
#define SS 2048
#define HD 1024
#define HE 1024
#define MM (NB * SS)   // compacted (padded) row space
#define NT 32          // K-tiles = HE/32

typedef float f32x4 __attribute__((ext_vector_type(4)));
typedef short bf16x8 __attribute__((ext_vector_type(8)));
typedef short short4v __attribute__((ext_vector_type(4)));

static __device__ __forceinline__ short f2bf(float f) {
    union { __hip_bfloat16 h; short s; } u;
    u.h = __float2bfloat16(f);
    return u.s;
}
static __device__ __forceinline__ float bf2f(short s) {
    union { float f; unsigned u; } u;
    u.u = ((unsigned)(unsigned short)s) << 16;
    return u.f;
}

static __device__ __forceinline__ void gload16(const void* g, const void* l) {
    __builtin_amdgcn_global_load_lds(
        (const __attribute__((address_space(1))) void*)(uintptr_t)(g),
        (__attribute__((address_space(3))) void*)(unsigned)(uintptr_t)(l),
        16, 0, 0);
}

// ---------------- per-batch mask compaction: 1 wave per batch ----------------
__global__ __launch_bounds__(64) void compact_kernel(const int* __restrict__ mask,
                                                     int* __restrict__ idx,
                                                     int* __restrict__ cnt) {
    const int b = blockIdx.x;
    const int lane = threadIdx.x;
    int base = 0;
    for (int s0 = 0; s0 < SS; s0 += 64) {
        const int m = mask[b * SS + s0 + lane];
        const unsigned long long bal = __ballot(m != 0);
        const int rank = __popcll(bal & ((1ull << lane) - 1ull));
        if (m) idx[b * SS + base + rank] = s0 + lane;
        base += (int)__popcll(bal);
    }
    if (lane == 0) cnt[b] = base;
    for (int j = base + lane; j < SS; j += 64) idx[b * SS + j] = 0;
}

// ---------------- f32 -> bf16 (Wk) ----------------
__global__ __launch_bounds__(256) void cvt_bf16_kernel(const float* __restrict__ in,
                                                       short* __restrict__ out, int n8) {
    int i = blockIdx.x * 256 + threadIdx.x;
    const int stride = gridDim.x * 256;
    for (; i < n8; i += stride) {
        const f32x4 a = *(const f32x4*)(in + (long)i * 8);
        const f32x4 b = *(const f32x4*)(in + (long)i * 8 + 4);
        bf16x8 o;
        o[0] = f2bf(a[0]); o[1] = f2bf(a[1]); o[2] = f2bf(a[2]); o[3] = f2bf(a[3]);
        o[4] = f2bf(b[0]); o[5] = f2bf(b[1]); o[6] = f2bf(b[2]); o[7] = f2bf(b[3]);
        *(bf16x8*)(out + (long)i * 8) = o;
    }
}

// ---------------- gather + cvt enc rows -> compacted bf16, zero-pad to 128 ----------------
__global__ __launch_bounds__(256) void cvt_enc_kernel(const float* __restrict__ enc,
                                                      const int* __restrict__ idx,
                                                      const int* __restrict__ cnt,
                                                      short* __restrict__ encb) {
    const int b  = blockIdx.x >> 7;
    const int j0 = (blockIdx.x & 127) * 16;
    const int n  = cnt[b];
    const int nr = (n + 127) & ~127;
    if (j0 >= nr) return;
    const int j  = j0 + (threadIdx.x >> 4);
    const int c0 = (threadIdx.x & 15) * 8;
    short* dst = encb + ((long)b * SS + j) * HE + c0;
    if (j < n) {
        const float* src = enc + ((long)b * SS + idx[b * SS + j]) * HE + c0;
        #pragma unroll
        for (int u = 0; u < 8; ++u) {
            const f32x4 x = *(const f32x4*)(src + u * 128);
            const f32x4 y = *(const f32x4*)(src + u * 128 + 4);
            bf16x8 o;
            o[0] = f2bf(x[0]); o[1] = f2bf(x[1]); o[2] = f2bf(x[2]); o[3] = f2bf(x[3]);
            o[4] = f2bf(y[0]); o[5] = f2bf(y[1]); o[6] = f2bf(y[2]); o[7] = f2bf(y[3]);
            *(bf16x8*)(dst + u * 128) = o;
        }
    } else {
        const bf16x8 z = (bf16x8){0,0,0,0,0,0,0,0};
        #pragma unroll
        for (int u = 0; u < 8; ++u) *(bf16x8*)(dst + u * 128) = z;
    }
}

// ---------------- q = dh @ Wq^T ----------------
__global__ __launch_bounds__(256) void qproj_kernel(const float* __restrict__ dh,
                                                    const float* __restrict__ Wq,
                                                    float* __restrict__ q) {
    const int wid  = threadIdx.x >> 6;
    const int lane = threadIdx.x & 63;
    const int d    = blockIdx.x * 4 + wid;
    const float* wrow = Wq + (long)d * HD + lane * 16;
    f32x4 w0 = *(const f32x4*)(wrow + 0);
    f32x4 w1 = *(const f32x4*)(wrow + 4);
    f32x4 w2 = *(const f32x4*)(wrow + 8);
    f32x4 w3 = *(const f32x4*)(wrow + 12);
    for (int b = 0; b < NB; ++b) {
        const float* drow = dh + b * HD + lane * 16;
        f32x4 d0 = *(const f32x4*)(drow + 0);
        f32x4 d1 = *(const f32x4*)(drow + 4);
        f32x4 d2 = *(const f32x4*)(drow + 8);
        f32x4 d3 = *(const f32x4*)(drow + 12);
        f32x4 s4 = w0 * d0 + w1 * d1 + w2 * d2 + w3 * d3;
        float dot = s4[0] + s4[1] + s4[2] + s4[3];
        #pragma unroll
        for (int off = 32; off > 0; off >>= 1)
            dot += __shfl_xor(dot, off, 64);
        if (lane == 0) q[b * HD + d] = dot;
    }
}

// ---------------- score GEMM: 128x128 tile, 4 waves, 2 K-tiles per epoch ----------------
__global__ __launch_bounds__(256, 3) void score_mfma_kernel(const short* __restrict__ encb,
                                                            const short* __restrict__ wkb,
                                                            const float* __restrict__ qv,
                                                            const float* __restrict__ ven,
                                                            const int* __restrict__ cnt,
                                                            float* __restrict__ sp) {
    __shared__ __align__(16) short As[2][4096];   // two 8 KB A tiles (K-subtiles)
    __shared__ __align__(16) short Bs[2][4096];   // two 8 KB B tiles

    // XCD swizzle: 8 sibling N-tiles of an M-tile on one XCD (A L2 reuse)
    const int bid   = blockIdx.x;
    const int xcd   = bid & 7;
    const int slot  = bid >> 3;                 // 0..511
    const int mtile = xcd * 64 + (slot >> 3);   // 0..511
    const int nt    = slot & 7;                 // 0..7

    const int bb   = mtile >> 4;
    const int tile = mtile & 15;
    if (tile * 128 >= cnt[bb]) return;          // masked tail tile: dead

    const int tid  = threadIdx.x;
    const int lane = tid & 63;
    const int wid  = tid >> 6;
    const int wr   = wid >> 1;
    const int wc   = wid & 1;
    const long mbase = (long)bb * SS + tile * 128;   // compacted row base
    const int  nbase = nt * 128;

    f32x4 acc[4][4];
    #pragma unroll
    for (int m = 0; m < 4; ++m)
        #pragma unroll
        for (int n = 0; n < 4; ++n)
            acc[m][n] = (f32x4){0.f, 0.f, 0.f, 0.f};

    // staging: chunk c = tid, tid+256 -> row c>>2, k-slot c&3
    const short* ag0 = encb + (mbase + (tid >> 2)) * (long)HE + (tid & 3) * 8;
    const short* ag1 = ag0 + 64 * (long)HE;
    const short* bg0 = wkb + ((long)(nbase + (tid >> 2))) * HE + (tid & 3) * 8;
    const short* bg1 = bg0 + 64 * (long)HE;

    const int frow = lane & 15;
    const int kby  = (lane >> 4) * 16;

    #define COMPUTE(BUF)                                                         \
        do {                                                                     \
            bf16x8 af[4], bfr[4];                                                \
            _Pragma("unroll")                                                    \
            for (int m = 0; m < 4; ++m)                                          \
                af[m] = *(const bf16x8*)((const char*)As[BUF]                    \
                          + (wr * 64 + m * 16 + frow) * 64 + kby);               \
            _Pragma("unroll")                                                    \
            for (int n = 0; n < 4; ++n)                                          \
                bfr[n] = *(const bf16x8*)((const char*)Bs[BUF]                   \
                          + (wc * 64 + n * 16 + frow) * 64 + kby);               \
            _Pragma("unroll")                                                    \
            for (int m = 0; m < 4; ++m)                                          \
                _Pragma("unroll")                                                \
                for (int n = 0; n < 4; ++n)                                      \
                    acc[m][n] = __builtin_amdgcn_mfma_f32_16x16x32_bf16(         \
                        af[m], bfr[n], acc[m][n], 0, 0, 0);                      \
        } while (0)

    // 16 epochs, each staging + computing 2 K-tiles (one drain+barrier pair per epoch)
    for (int kt = 0; kt < NT; kt += 2) {
        const int ko0 = kt * 32;
        const int ko1 = ko0 + 32;
        gload16(ag0 + ko0, (char*)As[0] + wid * 1024);
        gload16(ag1 + ko0, (char*)As[0] + 4096 + wid * 1024);
        gload16(bg0 + ko0, (char*)Bs[0] + wid * 1024);
        gload16(bg1 + ko0, (char*)Bs[0] + 4096 + wid * 1024);
        gload16(ag0 + ko1, (char*)As[1] + wid * 1024);
        gload16(ag1 + ko1, (char*)As[1] + 4096 + wid * 1024);
        gload16(bg0 + ko1, (char*)Bs[1] + wid * 1024);
        gload16(bg1 + ko1, (char*)Bs[1] + 4096 + wid * 1024);
        __syncthreads();   // drains all 8 gloads, joins waves
        COMPUTE(0);
        COMPUTE(1);
        __syncthreads();   // LDS reads done before next epoch overwrites
    }
    #undef COMPUTE

    // epilogue: partial score over this wave's 64 cols; C/D: col=lane&15, row=(lane>>4)*4+reg
    float qq[4], vv[4];
    #pragma unroll
    for (int n = 0; n < 4; ++n) {
        const int c = nbase + wc * 64 + n * 16 + frow;
        qq[n] = qv[bb * HD + c];
        vv[n] = ven[c];
    }
    float p[4][4];
    #pragma unroll
    for (int m = 0; m < 4; ++m) {
        #pragma unroll
        for (int rg = 0; rg < 4; ++rg) {
            float s = 0.f;
            #pragma unroll
            for (int n = 0; n < 4; ++n) {
                const float x = acc[m][n][rg] + qq[n];
                const float e = __expf(2.f * x);
                const float t = 1.f - 2.f * __builtin_amdgcn_rcpf(e + 1.f);
                s += vv[n] * t;
            }
            #pragma unroll
            for (int msk = 1; msk <= 8; msk <<= 1)
                s += __shfl_xor(s, msk, 64);
            p[m][rg] = s;
        }
    }
    if ((lane & 15) == 0) {
        const int g = lane >> 4;
        float* dst = sp + (long)(nt * 2 + wc) * MM;   // 16 deterministic partial slots
        #pragma unroll
        for (int m = 0; m < 4; ++m)
            #pragma unroll
            for (int rg = 0; rg < 4; ++rg)
                dst[mbase + wr * 64 + m * 16 + g * 4 + rg] = p[m][rg];
    }
}

// ---------------- softmax over compacted domain; zero + scatter to attn ----------------
__global__ __launch_bounds__(256) void softmax_kernel(const float* __restrict__ sp,
                                                      const int* __restrict__ idx,
                                                      const int* __restrict__ cnt,
                                                      float* __restrict__ attn,
                                                      float* __restrict__ wcomp) {
    const int b = blockIdx.x;
    const int tid = threadIdx.x;
    const int lane = tid & 63;
    const int wid = tid >> 6;
    const int n = cnt[b];
    // dense zero of this batch's attn row (scatter after the reduction barriers)
    #pragma unroll
    for (int i = 0; i < 8; ++i)
        attn[b * SS + tid + i * 256] = 0.f;
    __shared__ float red[4];
    float sc[8];
    float mx = -3.0e38f;
    #pragma unroll
    for (int i = 0; i < 8; ++i) {
        const int j = tid + i * 256;
        float v = -3.0e38f;
        if (j < n) {
            v = 0.f;
            #pragma unroll
            for (int k = 0; k < 16; ++k)
                v += sp[(long)k * MM + b * SS + j];
        }
        sc[i] = v;
        mx = fmaxf(mx, v);
    }
    #pragma unroll
    for (int off = 32; off > 0; off >>= 1)
        mx = fmaxf(mx, __shfl_xor(mx, off, 64));
    if (lane == 0) red[wid] = mx;
    __syncthreads();
    mx = fmaxf(fmaxf(red[0], red[1]), fmaxf(red[2], red[3]));
    __syncthreads();
    float sum = 0.f;
    #pragma unroll
    for (int i = 0; i < 8; ++i) {
        const float e = (sc[i] > -1.0e38f) ? __expf(sc[i] - mx) : 0.f;
        sc[i] = e;
        sum += e;
    }
    #pragma unroll
    for (int off = 32; off > 0; off >>= 1)
        sum += __shfl_xor(sum, off, 64);
    if (lane == 0) red[wid] = sum;
    __syncthreads();
    sum = red[0] + red[1] + red[2] + red[3];
    const float inv = 1.f / sum;
    #pragma unroll
    for (int i = 0; i < 8; ++i) {
        const int j = tid + i * 256;
        const float w = sc[i] * inv;
        wcomp[b * SS + j] = w;                    // exact 0 beyond cnt
        if (j < n) attn[b * SS + idx[b * SS + j]] = w;
    }
}

// ---------------- context over compacted bf16 rows ----------------
__global__ __launch_bounds__(256) void ctx_partial_kernel(const short* __restrict__ encb,
                                                          const float* __restrict__ wcomp,
                                                          const int* __restrict__ cnt,
                                                          float* __restrict__ cp) {
    const int b = blockIdx.x >> 5;
    const int chunk = blockIdx.x & 31;
    const int tid = threadIdx.x;
    float* dst = cp + ((long)(b * 32 + chunk)) * HE + tid * 4;
    if (chunk * 64 >= cnt[b]) {
        *(f32x4*)dst = (f32x4){0.f, 0.f, 0.f, 0.f};
        return;
    }
    const short* ep = encb + ((long)b * SS + chunk * 64) * HE + tid * 4;
    const float* ap = wcomp + b * SS + chunk * 64;
    f32x4 acc = (f32x4){0.f, 0.f, 0.f, 0.f};
    #pragma unroll 4
    for (int s = 0; s < 64; ++s) {
        const float w = ap[s];
        const short4v v = *(const short4v*)(ep + (long)s * HE);
        acc[0] += w * bf2f(v[0]);
        acc[1] += w * bf2f(v[1]);
        acc[2] += w * bf2f(v[2]);
        acc[3] += w * bf2f(v[3]);
    }
    *(f32x4*)dst = acc;
}

__global__ __launch_bounds__(256) void ctx_reduce_kernel(const float* __restrict__ cp,
                                                         float* __restrict__ out) {
    const int o = blockIdx.x * 256 + threadIdx.x;
    const int b = o >> 10;
    const int e = o & 1023;
    float s = 0.f;
    #pragma unroll
    for (int c = 0; c < 32; ++c)
        s += cp[((long)(b * 32 + c)) * HE + e];
    out[o] = s;
}

extern "C" void kernel_launch(void* const* d_in, const int* in_sizes, int n_in,
                              void* d_out, int out_size, void* d_ws, size_t ws_size,
                              hipStream_t stream) {
    const float* dh   = (const float*)d_in[0];
    const float* enc  = (const float*)d_in[1];
    const int*   mask = (const int*)d_in[2];
    const float* Wq   = (const float*)d_in[3];
    const float* Wk   = (const float*)d_in[4];
    const float* Ve   = (const float*)d_in[5];

    float* out  = (float*)d_out;
    float* ctx  = out;
    float* attn = out + NB * HD;

    float* ws    = (float*)d_ws;
    float* wq_   = ws;                            // 32768 f
    float* sp    = ws + 32768;                    // 16 * 65536 f (4 MB)
    float* cp    = sp + 16 * (long)MM;            // 32*32*1024 f (4 MB)
    short* wkb   = (short*)(cp + 32 * 32 * HE);   // 1M bf16 (2 MB)
    float* wcomp = (float*)(wkb + (long)HD * HE); // 65536 f
    int*   idx   = (int*)(wcomp + MM);            // 65536 i
    int*   cnt   = idx + MM;                      // 32 i (+pad)
    short* encb  = (short*)(cnt + 64);            // 67.1M bf16 (128 MB)

    compact_kernel<<<NB, 64, 0, stream>>>(mask, idx, cnt);
    qproj_kernel<<<256, 256, 0, stream>>>(dh, Wq, wq_);
    cvt_bf16_kernel<<<512, 256, 0, stream>>>(Wk, wkb, HD * HE / 8);
    cvt_enc_kernel<<<NB * 128, 256, 0, stream>>>(enc, idx, cnt, encb);
    score_mfma_kernel<<<4096, 256, 0, stream>>>(encb, wkb, wq_, Ve, cnt, sp);
    softmax_kernel<<<NB, 256, 0, stream>>>(sp, idx, cnt, attn, wcomp);
    ctx_partial_kernel<<<1024, 256, 0, stream>>>(encb, wcomp, cnt, cp);
    ctx_reduce_kernel<<<128, 256, 0, stream>>>(cp, ctx);
}